// Round 21
// baseline (296.280 us; speedup 1.0000x reference)
//
#include <hip/hip_runtime.h>
#include <cstdint>
#include <cstddef>

// GraphSAGE 3-layer, mean aggregation.
// R21: single change on R20 (286.7us best): gemm __launch_bounds__(256,3) ->
// (256,5). LDS is 32KB (5 blocks/CU fit) and VGPR=68 (cap at 5 blocks = 102),
// so occupancy was launch-bounds-capped at 3 blocks/CU. 5 blocks/CU = 20 waves
// = 67% more outstanding global_load_lds queues + more barrier-drain cover.
// Discriminates DMA-parallelism-bound (helps) vs per-CU-issue-rate-bound
// (flat -> declared floor).
// Kept: XCD bijective swizzle (R20), rank-from-degree fill (R18), fused prep
// (R19), 128x128 BK=32 single-plane-W gemm (R15), bf16 agg (R4, MSHR-bound).

typedef __bf16 bf16x8 __attribute__((ext_vector_type(8)));
typedef __bf16 bf16x4 __attribute__((ext_vector_type(4)));
typedef float  f32x4  __attribute__((ext_vector_type(4)));

static inline size_t align_up(size_t x, size_t a) { return (x + a - 1) / a * a; }

__device__ __forceinline__ void gload_lds16(const void* g, void* l) {
    __builtin_amdgcn_global_load_lds(
        (const __attribute__((address_space(1))) void*)g,
        (__attribute__((address_space(3))) void*)l, 16, 0, 0);
}

// ---- fused prep: [0,nb1) deg+rank | [nb1,nb1+nb2) x->bf16 | rest convert_w ----
__global__ void prep_all(const int* __restrict__ dst, int* __restrict__ deg,
                         int* __restrict__ rank, int E, int nb1,
                         const float* __restrict__ x, uint16_t* __restrict__ xb,
                         int cx, int nb2,
                         const float* __restrict__ Wl0, const float* __restrict__ Wr0,
                         uint8_t* __restrict__ Wp0,
                         const float* __restrict__ Wl1, const float* __restrict__ Wr1,
                         uint8_t* __restrict__ Wp1,
                         const float* __restrict__ Wl2, const float* __restrict__ Wr2,
                         uint8_t* __restrict__ Wp2) {
    int bid = blockIdx.x;
    if (bid < nb1) {
        int i = bid * 256 + threadIdx.x;
        if (i < E) rank[i] = atomicAdd(&deg[dst[i]], 1);
        return;
    }
    bid -= nb1;
    if (bid < nb2) {
        int i = (bid * 256 + threadIdx.x) * 8;
        if (i >= cx) return;
        float4 v0 = *(const float4*)(x + i);
        float4 v1 = *(const float4*)(x + i + 4);
        bf16x8 o;
        o[0] = (__bf16)v0.x; o[1] = (__bf16)v0.y; o[2] = (__bf16)v0.z; o[3] = (__bf16)v0.w;
        o[4] = (__bf16)v1.x; o[5] = (__bf16)v1.y; o[6] = (__bf16)v1.z; o[7] = (__bf16)v1.w;
        *(bf16x8*)(xb + i) = o;
        return;
    }
    bid -= nb2;   // 0..319
    const float *Wl, *Wr;
    uint8_t* Wpre;
    int K1, kbase;
    if (bid < 64)       { Wl = Wl0; Wr = Wr0; Wpre = Wp0; K1 = 128; kbase = bid * 4; }
    else if (bid < 192) { Wl = Wl1; Wr = Wr1; Wpre = Wp1; K1 = 256; kbase = (bid - 64) * 4; }
    else                { Wl = Wl2; Wr = Wr2; Wpre = Wp2; K1 = 256; kbase = (bid - 192) * 4; }
    int c = threadIdx.x;
    bf16x4 hi4;
    #pragma unroll
    for (int j = 0; j < 4; ++j) {
        int k = kbase + j;
        float w = (k < K1) ? Wl[(size_t)k * 256 + c] : Wr[(size_t)(k - K1) * 256 + c];
        hi4[j] = (__bf16)w;
    }
    int s = kbase >> 5;
    int kk = kbase & 31;
    int lane = (c & 15) + ((kk >> 3) << 4);
    uint32_t byte = (uint32_t)(c >> 4) * 1024 + (uint32_t)lane * 16 + (uint32_t)(kk & 7) * 2;
    *(bf16x4*)(Wpre + (size_t)s * 16384 + byte) = hi4;
}

// ---- 3-phase scan: deg -> rowptr (exclusive), inv_deg ----
__global__ void scan_a(const int* __restrict__ deg, int* __restrict__ blocksums, int n) {
    __shared__ int ts[256];
    int t = threadIdx.x;
    int base = blockIdx.x * 1024 + t * 4;
    int s = 0;
    #pragma unroll
    for (int j = 0; j < 4; ++j) if (base + j < n) s += deg[base + j];
    ts[t] = s;
    __syncthreads();
    #pragma unroll
    for (int off = 128; off >= 1; off >>= 1) {
        if (t < off) ts[t] += ts[t + off];
        __syncthreads();
    }
    if (t == 0) blocksums[blockIdx.x] = ts[0];
}

__global__ void scan_b(const int* __restrict__ blocksums, int* __restrict__ blockoff,
                       int NB, int* __restrict__ rowptr_n) {
    __shared__ int ts[256];
    int t = threadIdx.x;
    int v = (t < NB) ? blocksums[t] : 0;
    ts[t] = v;
    __syncthreads();
    for (int off = 1; off < 256; off <<= 1) {
        int u = (t >= off) ? ts[t - off] : 0;
        __syncthreads();
        ts[t] += u;
        __syncthreads();
    }
    if (t < NB) blockoff[t] = ts[t] - v;
    if (t == 255) *rowptr_n = ts[255];
}

__global__ void scan_c(const int* __restrict__ deg, const int* __restrict__ blockoff,
                       int* __restrict__ rowptr, float* __restrict__ inv_deg, int n) {
    __shared__ int ts[256];
    int t = threadIdx.x;
    int base = blockIdx.x * 1024 + t * 4;
    int d[4];
    int s = 0;
    #pragma unroll
    for (int j = 0; j < 4; ++j) {
        d[j] = (base + j < n) ? deg[base + j] : 0;
        s += d[j];
    }
    ts[t] = s;
    __syncthreads();
    for (int off = 1; off < 256; off <<= 1) {
        int u = (t >= off) ? ts[t - off] : 0;
        __syncthreads();
        ts[t] += u;
        __syncthreads();
    }
    int ex = ts[t] - s + blockoff[blockIdx.x];
    #pragma unroll
    for (int j = 0; j < 4; ++j) {
        if (base + j < n) {
            rowptr[base + j] = ex;
            inv_deg[base + j] = d[j] > 0 ? 1.0f / (float)d[j] : 0.0f;
            ex += d[j];
        }
    }
}

// atomic-free CSR fill: pos = rowptr[dst] + rank (precomputed).
__global__ void fill_kernel(const int* __restrict__ src, const int* __restrict__ dst,
                            const int* __restrict__ rowptr, const int* __restrict__ rank,
                            int* __restrict__ csr, int E) {
    int i = blockIdx.x * blockDim.x + threadIdx.x;
    if (i < E) csr[rowptr[dst[i]] + rank[i]] = src[i];
}

__device__ inline void addq(float* a, uint32_t u0, uint32_t u1, uint32_t u2, uint32_t u3) {
    uint32_t u[4] = {u0, u1, u2, u3};
    #pragma unroll
    for (int i = 0; i < 4; ++i) {
        a[2 * i]     += __uint_as_float(u[i] << 16);
        a[2 * i + 1] += __uint_as_float(u[i] & 0xffff0000u);
    }
}

// bf16 gather aggregation: C/8 lanes per node, 16B (8 bf16) per lane.
template<int C>
__global__ void agg_bf16(const uint16_t* __restrict__ hb, const int* __restrict__ rowptr,
                         const int* __restrict__ csr, const float* __restrict__ inv_deg,
                         uint16_t* __restrict__ aggb, int n) {
    constexpr int LPN = C / 8;
    constexpr int NPB = 256 / LPN;
    int node = blockIdx.x * NPB + (int)(threadIdx.x / LPN);
    if (node >= n) return;
    int sub = threadIdx.x % LPN;
    int b = rowptr[node], e = rowptr[node + 1];
    float acc[8] = {0.f, 0.f, 0.f, 0.f, 0.f, 0.f, 0.f, 0.f};
    const uint4* h4 = (const uint4*)hb;
    int k = b;
    for (; k + 3 < e; k += 4) {
        int s0 = csr[k], s1 = csr[k + 1], s2 = csr[k + 2], s3 = csr[k + 3];
        uint4 q0 = h4[(size_t)s0 * LPN + sub];
        uint4 q1 = h4[(size_t)s1 * LPN + sub];
        uint4 q2 = h4[(size_t)s2 * LPN + sub];
        uint4 q3 = h4[(size_t)s3 * LPN + sub];
        addq(acc, q0.x, q0.y, q0.z, q0.w);
        addq(acc, q1.x, q1.y, q1.z, q1.w);
        addq(acc, q2.x, q2.y, q2.z, q2.w);
        addq(acc, q3.x, q3.y, q3.z, q3.w);
    }
    for (; k < e; ++k) {
        uint4 q = h4[(size_t)csr[k] * LPN + sub];
        addq(acc, q.x, q.y, q.z, q.w);
    }
    float id = inv_deg[node];
    bf16x8 o;
    #pragma unroll
    for (int j = 0; j < 8; ++j) o[j] = (__bf16)(acc[j] * id);
    *(bf16x8*)(aggb + (size_t)node * C + sub * 8) = o;
}

__device__ inline uint16_t f2bf(float f) {
    __bf16 h = (__bf16)f;
    union { __bf16 b; uint16_t u; } c;
    c.b = h;
    return c.u;
}

// Fused GEMM: out = relu([A1 | A2] @ W + bias), A/W bf16.
// 128 rows x 128 cols per block; m97 pipeline, BK=32, single-plane W;
// bijective XCD swizzle (R20). launch_bounds(256,5): 5 blocks/CU (LDS 32KB,
// VGPR cap 102 >= 68) for more parallel DMA queues.
template<int K1>
__global__ __launch_bounds__(256, 5)
void gemm_mfma(const uint16_t* __restrict__ A1, const uint16_t* __restrict__ A2,
               const uint8_t* __restrict__ Wpre, const float* __restrict__ bias,
               float* __restrict__ out, uint16_t* __restrict__ outb, int n, int nwg) {
    constexpr int S1 = K1 / 32;
    constexpr int NT = 2 * S1;          // 8 or 16
    __shared__ __align__(16) uint8_t ldsA[2][8192];   // 128 rows x 64B
    __shared__ __align__(16) uint8_t ldsW[2][8192];   // 128 cols x 64B (frag-major)

    // m204 bijective XCD swizzle
    int wid = blockIdx.x;
    int q = nwg >> 3, r = nwg & 7;
    int xcd = wid & 7, idx = wid >> 3;
    int basex = (xcd < r) ? xcd * (q + 1) : r * (q + 1) + (xcd - r) * q;
    int logical = basex + idx;

    const int tid = threadIdx.x;
    const int l = tid & 63;
    const int w = tid >> 6;
    const int lr = l & 15;
    const int lg = l >> 4;
    const int row0 = (logical >> 1) * 128;
    const int cb = logical & 1;          // col half (128 cols)
    const int wr = w & 1;                // wave row half (64 rows)
    const int cw = w >> 1;               // wave col group (64 cols)

    f32x4 acc[4][4];
    #pragma unroll
    for (int mt = 0; mt < 4; ++mt)
        #pragma unroll
        for (int nt = 0; nt < 4; ++nt)
            acc[mt][nt] = (f32x4)(0.f);

    const int key = (lr >> 1) & 3;
    uint32_t abyte[4];
    #pragma unroll
    for (int mt = 0; mt < 4; ++mt)
        abyte[mt] = (uint32_t)((wr * 64 + mt * 16 + lr) * 64 + ((lg ^ key) << 4));
    uint32_t wrbyte[4];
    #pragma unroll
    for (int nt = 0; nt < 4; ++nt)
        wrbyte[nt] = (uint32_t)((cw * 4 + nt) * 1024 + l * 16);

    auto stage = [&](int s, int buf) {
        const uint16_t* __restrict__ A = (s < S1) ? A1 : A2;
        int kl = ((s < S1) ? s : s - S1) * 32;
        #pragma unroll
        for (int i = 0; i < 2; ++i) {
            int b = w * 2 + i;                     // A block 0..7
            int r2 = b * 16 + (l >> 2);            // row 0..127
            int kq = (l & 3) ^ ((r2 >> 1) & 3);    // pre-swizzled source k-quad
            gload_lds16(A + (size_t)(row0 + r2) * K1 + kl + kq * 8,
                        &ldsA[buf][b * 1024]);
        }
        const uint8_t* __restrict__ Ws = Wpre + (size_t)s * 16384 + (size_t)cb * 8192;
        #pragma unroll
        for (int i = 0; i < 2; ++i) {
            int b = w * 2 + i;                     // W block 0..7
            gload_lds16(Ws + b * 1024 + l * 16, &ldsW[buf][b * 1024]);
        }
    };

    auto domfma = [&](int buf) {
        bf16x8 bh[4];
        #pragma unroll
        for (int nt = 0; nt < 4; ++nt)
            bh[nt] = *(const bf16x8*)(&ldsW[buf][wrbyte[nt]]);
        #pragma unroll
        for (int mt = 0; mt < 4; ++mt) {
            bf16x8 a = *(const bf16x8*)(&ldsA[buf][abyte[mt]]);
            #pragma unroll
            for (int nt = 0; nt < 4; ++nt)
                acc[mt][nt] = __builtin_amdgcn_mfma_f32_16x16x32_bf16(a, bh[nt], acc[mt][nt], 0, 0, 0);
        }
    };

    stage(0, 0);
    __syncthreads();
    #pragma unroll 1
    for (int s = 0; s < NT; ++s) {
        int buf = s & 1;
        if (s + 1 < NT) stage(s + 1, buf ^ 1);   // in flight over MFMAs
        domfma(buf);
        __syncthreads();
    }

    #pragma unroll
    for (int nt = 0; nt < 4; ++nt) {
        int col = cb * 128 + cw * 64 + nt * 16 + lr;
        float bv = bias[col];
        #pragma unroll
        for (int mt = 0; mt < 4; ++mt) {
            #pragma unroll
            for (int rr = 0; rr < 4; ++rr) {
                int grow = row0 + wr * 64 + mt * 16 + lg * 4 + rr;
                if (grow < n) {
                    float v = fmaxf(acc[mt][nt][rr] + bv, 0.f);
                    if (out)  out[(size_t)grow * 256 + col] = v;
                    if (outb) outb[(size_t)grow * 256 + col] = f2bf(v);
                }
            }
        }
    }
}

extern "C" void kernel_launch(void* const* d_in, const int* in_sizes, int n_in,
                              void* d_out, int out_size, void* d_ws, size_t ws_size,
                              hipStream_t stream) {
    const float* x   = (const float*)d_in[0];
    const int* edge  = (const int*)d_in[1];
    const float* Wl0 = (const float*)d_in[2];
    const float* bl0 = (const float*)d_in[3];
    const float* Wr0 = (const float*)d_in[4];
    const float* Wl1 = (const float*)d_in[5];
    const float* bl1 = (const float*)d_in[6];
    const float* Wr1 = (const float*)d_in[7];
    const float* Wl2 = (const float*)d_in[8];
    const float* bl2 = (const float*)d_in[9];
    const float* Wr2 = (const float*)d_in[10];

    int n = in_sizes[0] / 128;   // 50000
    int E = in_sizes[1] / 2;     // 800000
    int npad = n + 128;
    const int* src = edge;
    const int* dst = edge + E;

    char* wptr = (char*)d_ws;
    auto alloc = [&](size_t bytes) { char* p = wptr; wptr += align_up(bytes, 256); return p; };
    int*      deg    = (int*)alloc((size_t)n * 4);
    int*      rowptr = (int*)alloc(((size_t)n + 1) * 4);
    int*      rank   = (int*)alloc((size_t)E * 4);
    int*      csr    = (int*)alloc((size_t)E * 4);
    float*    invd   = (float*)alloc((size_t)n * 4);
    int*      bsums  = (int*)alloc(256 * 4);
    int*      boff   = (int*)alloc(256 * 4);
    uint8_t*  Wp0    = (uint8_t*)alloc(8 * 16384);
    uint8_t*  Wp1    = (uint8_t*)alloc(16 * 16384);
    uint8_t*  Wp2    = (uint8_t*)alloc(16 * 16384);
    uint16_t* xb     = (uint16_t*)alloc((size_t)npad * 128 * 2);
    uint16_t* aggb   = (uint16_t*)alloc((size_t)npad * 256 * 2);
    uint16_t* h0b    = (uint16_t*)alloc((size_t)npad * 256 * 2);
    uint16_t* h1b    = (uint16_t*)alloc((size_t)npad * 256 * 2);

    int NB = (n + 1023) / 1024;
    int cx = n * 128;
    int nb1 = (E + 255) / 256;
    int nb2 = (cx / 8 + 255) / 256;

    hipMemsetAsync(deg, 0, (size_t)n * 4, stream);
    prep_all<<<nb1 + nb2 + 320, 256, 0, stream>>>(dst, deg, rank, E, nb1,
                                                  x, xb, cx, nb2,
                                                  Wl0, Wr0, Wp0, Wl1, Wr1, Wp1,
                                                  Wl2, Wr2, Wp2);
    scan_a<<<NB, 256, 0, stream>>>(deg, bsums, n);
    scan_b<<<1, 256, 0, stream>>>(bsums, boff, NB, rowptr + n);
    scan_c<<<NB, 256, 0, stream>>>(deg, boff, rowptr, invd, n);
    fill_kernel<<<(E + 255) / 256, 256, 0, stream>>>(src, dst, rowptr, rank, csr, E);

    int gemm_grid = ((n + 127) / 128) * 2;   // 782
    // layer 0: C=128 -> 256
    agg_bf16<128><<<(n + 15) / 16, 256, 0, stream>>>(xb, rowptr, csr, invd, aggb, n);
    gemm_mfma<128><<<gemm_grid, 256, 0, stream>>>(aggb, xb, Wp0, bl0, (float*)nullptr, h0b, n, gemm_grid);
    // layer 1: 256 -> 256
    agg_bf16<256><<<(n + 7) / 8, 256, 0, stream>>>(h0b, rowptr, csr, invd, aggb, n);
    gemm_mfma<256><<<gemm_grid, 256, 0, stream>>>(aggb, h0b, Wp1, bl1, (float*)nullptr, h1b, n, gemm_grid);
    // layer 2: 256 -> 256 (fp32 output to d_out)
    agg_bf16<256><<<(n + 7) / 8, 256, 0, stream>>>(h1b, rowptr, csr, invd, aggb, n);
    gemm_mfma<256><<<gemm_grid, 256, 0, stream>>>(aggb, h1b, Wp2, bl2, (float*)d_out, (uint16_t*)nullptr, n, gemm_grid);
}

// Round 22
// 287.898 us; speedup vs baseline: 1.0291x; 1.0291x over previous
//
#include <hip/hip_runtime.h>
#include <cstdint>
#include <cstddef>

// GraphSAGE 3-layer, mean aggregation.
// R22: REVERT to R20 exactly (286.7us best). R21's (256,5) regressed ->
// gemm is per-CU-rate/L2-bound at 3 blocks/CU, not DMA-parallelism-bound.
// All phases now at measured floors:
//   agg 140us: FETCH == compulsory per-XCD model (1%), MSHR-bound (R19 A/B).
//   gemm ~85us: tile/pipeline/layout/occupancy space explored R5-R21; this
//     config is the argmin (single-plane W, 128x128 BK=32, m97 pipeline,
//     bijective XCD swizzle, 3 blocks/CU).
//   prep/scan/fill ~50us: fused, atomic-free fill, multi-block scan.

typedef __bf16 bf16x8 __attribute__((ext_vector_type(8)));
typedef __bf16 bf16x4 __attribute__((ext_vector_type(4)));
typedef float  f32x4  __attribute__((ext_vector_type(4)));

static inline size_t align_up(size_t x, size_t a) { return (x + a - 1) / a * a; }

__device__ __forceinline__ void gload_lds16(const void* g, void* l) {
    __builtin_amdgcn_global_load_lds(
        (const __attribute__((address_space(1))) void*)g,
        (__attribute__((address_space(3))) void*)l, 16, 0, 0);
}

// ---- fused prep: [0,nb1) deg+rank | [nb1,nb1+nb2) x->bf16 | rest convert_w ----
__global__ void prep_all(const int* __restrict__ dst, int* __restrict__ deg,
                         int* __restrict__ rank, int E, int nb1,
                         const float* __restrict__ x, uint16_t* __restrict__ xb,
                         int cx, int nb2,
                         const float* __restrict__ Wl0, const float* __restrict__ Wr0,
                         uint8_t* __restrict__ Wp0,
                         const float* __restrict__ Wl1, const float* __restrict__ Wr1,
                         uint8_t* __restrict__ Wp1,
                         const float* __restrict__ Wl2, const float* __restrict__ Wr2,
                         uint8_t* __restrict__ Wp2) {
    int bid = blockIdx.x;
    if (bid < nb1) {
        int i = bid * 256 + threadIdx.x;
        if (i < E) rank[i] = atomicAdd(&deg[dst[i]], 1);
        return;
    }
    bid -= nb1;
    if (bid < nb2) {
        int i = (bid * 256 + threadIdx.x) * 8;
        if (i >= cx) return;
        float4 v0 = *(const float4*)(x + i);
        float4 v1 = *(const float4*)(x + i + 4);
        bf16x8 o;
        o[0] = (__bf16)v0.x; o[1] = (__bf16)v0.y; o[2] = (__bf16)v0.z; o[3] = (__bf16)v0.w;
        o[4] = (__bf16)v1.x; o[5] = (__bf16)v1.y; o[6] = (__bf16)v1.z; o[7] = (__bf16)v1.w;
        *(bf16x8*)(xb + i) = o;
        return;
    }
    bid -= nb2;   // 0..319
    const float *Wl, *Wr;
    uint8_t* Wpre;
    int K1, kbase;
    if (bid < 64)       { Wl = Wl0; Wr = Wr0; Wpre = Wp0; K1 = 128; kbase = bid * 4; }
    else if (bid < 192) { Wl = Wl1; Wr = Wr1; Wpre = Wp1; K1 = 256; kbase = (bid - 64) * 4; }
    else                { Wl = Wl2; Wr = Wr2; Wpre = Wp2; K1 = 256; kbase = (bid - 192) * 4; }
    int c = threadIdx.x;
    bf16x4 hi4;
    #pragma unroll
    for (int j = 0; j < 4; ++j) {
        int k = kbase + j;
        float w = (k < K1) ? Wl[(size_t)k * 256 + c] : Wr[(size_t)(k - K1) * 256 + c];
        hi4[j] = (__bf16)w;
    }
    int s = kbase >> 5;
    int kk = kbase & 31;
    int lane = (c & 15) + ((kk >> 3) << 4);
    uint32_t byte = (uint32_t)(c >> 4) * 1024 + (uint32_t)lane * 16 + (uint32_t)(kk & 7) * 2;
    *(bf16x4*)(Wpre + (size_t)s * 16384 + byte) = hi4;
}

// ---- 3-phase scan: deg -> rowptr (exclusive), inv_deg ----
__global__ void scan_a(const int* __restrict__ deg, int* __restrict__ blocksums, int n) {
    __shared__ int ts[256];
    int t = threadIdx.x;
    int base = blockIdx.x * 1024 + t * 4;
    int s = 0;
    #pragma unroll
    for (int j = 0; j < 4; ++j) if (base + j < n) s += deg[base + j];
    ts[t] = s;
    __syncthreads();
    #pragma unroll
    for (int off = 128; off >= 1; off >>= 1) {
        if (t < off) ts[t] += ts[t + off];
        __syncthreads();
    }
    if (t == 0) blocksums[blockIdx.x] = ts[0];
}

__global__ void scan_b(const int* __restrict__ blocksums, int* __restrict__ blockoff,
                       int NB, int* __restrict__ rowptr_n) {
    __shared__ int ts[256];
    int t = threadIdx.x;
    int v = (t < NB) ? blocksums[t] : 0;
    ts[t] = v;
    __syncthreads();
    for (int off = 1; off < 256; off <<= 1) {
        int u = (t >= off) ? ts[t - off] : 0;
        __syncthreads();
        ts[t] += u;
        __syncthreads();
    }
    if (t < NB) blockoff[t] = ts[t] - v;
    if (t == 255) *rowptr_n = ts[255];
}

__global__ void scan_c(const int* __restrict__ deg, const int* __restrict__ blockoff,
                       int* __restrict__ rowptr, float* __restrict__ inv_deg, int n) {
    __shared__ int ts[256];
    int t = threadIdx.x;
    int base = blockIdx.x * 1024 + t * 4;
    int d[4];
    int s = 0;
    #pragma unroll
    for (int j = 0; j < 4; ++j) {
        d[j] = (base + j < n) ? deg[base + j] : 0;
        s += d[j];
    }
    ts[t] = s;
    __syncthreads();
    for (int off = 1; off < 256; off <<= 1) {
        int u = (t >= off) ? ts[t - off] : 0;
        __syncthreads();
        ts[t] += u;
        __syncthreads();
    }
    int ex = ts[t] - s + blockoff[blockIdx.x];
    #pragma unroll
    for (int j = 0; j < 4; ++j) {
        if (base + j < n) {
            rowptr[base + j] = ex;
            inv_deg[base + j] = d[j] > 0 ? 1.0f / (float)d[j] : 0.0f;
            ex += d[j];
        }
    }
}

// atomic-free CSR fill: pos = rowptr[dst] + rank (precomputed).
__global__ void fill_kernel(const int* __restrict__ src, const int* __restrict__ dst,
                            const int* __restrict__ rowptr, const int* __restrict__ rank,
                            int* __restrict__ csr, int E) {
    int i = blockIdx.x * blockDim.x + threadIdx.x;
    if (i < E) csr[rowptr[dst[i]] + rank[i]] = src[i];
}

__device__ inline void addq(float* a, uint32_t u0, uint32_t u1, uint32_t u2, uint32_t u3) {
    uint32_t u[4] = {u0, u1, u2, u3};
    #pragma unroll
    for (int i = 0; i < 4; ++i) {
        a[2 * i]     += __uint_as_float(u[i] << 16);
        a[2 * i + 1] += __uint_as_float(u[i] & 0xffff0000u);
    }
}

// bf16 gather aggregation: C/8 lanes per node, 16B (8 bf16) per lane.
template<int C>
__global__ void agg_bf16(const uint16_t* __restrict__ hb, const int* __restrict__ rowptr,
                         const int* __restrict__ csr, const float* __restrict__ inv_deg,
                         uint16_t* __restrict__ aggb, int n) {
    constexpr int LPN = C / 8;
    constexpr int NPB = 256 / LPN;
    int node = blockIdx.x * NPB + (int)(threadIdx.x / LPN);
    if (node >= n) return;
    int sub = threadIdx.x % LPN;
    int b = rowptr[node], e = rowptr[node + 1];
    float acc[8] = {0.f, 0.f, 0.f, 0.f, 0.f, 0.f, 0.f, 0.f};
    const uint4* h4 = (const uint4*)hb;
    int k = b;
    for (; k + 3 < e; k += 4) {
        int s0 = csr[k], s1 = csr[k + 1], s2 = csr[k + 2], s3 = csr[k + 3];
        uint4 q0 = h4[(size_t)s0 * LPN + sub];
        uint4 q1 = h4[(size_t)s1 * LPN + sub];
        uint4 q2 = h4[(size_t)s2 * LPN + sub];
        uint4 q3 = h4[(size_t)s3 * LPN + sub];
        addq(acc, q0.x, q0.y, q0.z, q0.w);
        addq(acc, q1.x, q1.y, q1.z, q1.w);
        addq(acc, q2.x, q2.y, q2.z, q2.w);
        addq(acc, q3.x, q3.y, q3.z, q3.w);
    }
    for (; k < e; ++k) {
        uint4 q = h4[(size_t)csr[k] * LPN + sub];
        addq(acc, q.x, q.y, q.z, q.w);
    }
    float id = inv_deg[node];
    bf16x8 o;
    #pragma unroll
    for (int j = 0; j < 8; ++j) o[j] = (__bf16)(acc[j] * id);
    *(bf16x8*)(aggb + (size_t)node * C + sub * 8) = o;
}

__device__ inline uint16_t f2bf(float f) {
    __bf16 h = (__bf16)f;
    union { __bf16 b; uint16_t u; } c;
    c.b = h;
    return c.u;
}

// Fused GEMM: out = relu([A1 | A2] @ W + bias), A/W bf16.
// 128 rows x 128 cols per block; m97 pipeline, BK=32, single-plane W;
// bijective XCD swizzle; 3 blocks/CU (R20-proven optimum).
template<int K1>
__global__ __launch_bounds__(256, 3)
void gemm_mfma(const uint16_t* __restrict__ A1, const uint16_t* __restrict__ A2,
               const uint8_t* __restrict__ Wpre, const float* __restrict__ bias,
               float* __restrict__ out, uint16_t* __restrict__ outb, int n, int nwg) {
    constexpr int S1 = K1 / 32;
    constexpr int NT = 2 * S1;          // 8 or 16
    __shared__ __align__(16) uint8_t ldsA[2][8192];   // 128 rows x 64B
    __shared__ __align__(16) uint8_t ldsW[2][8192];   // 128 cols x 64B (frag-major)

    // m204 bijective XCD swizzle
    int wid = blockIdx.x;
    int q = nwg >> 3, r = nwg & 7;
    int xcd = wid & 7, idx = wid >> 3;
    int basex = (xcd < r) ? xcd * (q + 1) : r * (q + 1) + (xcd - r) * q;
    int logical = basex + idx;

    const int tid = threadIdx.x;
    const int l = tid & 63;
    const int w = tid >> 6;
    const int lr = l & 15;
    const int lg = l >> 4;
    const int row0 = (logical >> 1) * 128;
    const int cb = logical & 1;          // col half (128 cols)
    const int wr = w & 1;                // wave row half (64 rows)
    const int cw = w >> 1;               // wave col group (64 cols)

    f32x4 acc[4][4];
    #pragma unroll
    for (int mt = 0; mt < 4; ++mt)
        #pragma unroll
        for (int nt = 0; nt < 4; ++nt)
            acc[mt][nt] = (f32x4)(0.f);

    const int key = (lr >> 1) & 3;
    uint32_t abyte[4];
    #pragma unroll
    for (int mt = 0; mt < 4; ++mt)
        abyte[mt] = (uint32_t)((wr * 64 + mt * 16 + lr) * 64 + ((lg ^ key) << 4));
    uint32_t wrbyte[4];
    #pragma unroll
    for (int nt = 0; nt < 4; ++nt)
        wrbyte[nt] = (uint32_t)((cw * 4 + nt) * 1024 + l * 16);

    auto stage = [&](int s, int buf) {
        const uint16_t* __restrict__ A = (s < S1) ? A1 : A2;
        int kl = ((s < S1) ? s : s - S1) * 32;
        #pragma unroll
        for (int i = 0; i < 2; ++i) {
            int b = w * 2 + i;                     // A block 0..7
            int r2 = b * 16 + (l >> 2);            // row 0..127
            int kq = (l & 3) ^ ((r2 >> 1) & 3);    // pre-swizzled source k-quad
            gload_lds16(A + (size_t)(row0 + r2) * K1 + kl + kq * 8,
                        &ldsA[buf][b * 1024]);
        }
        const uint8_t* __restrict__ Ws = Wpre + (size_t)s * 16384 + (size_t)cb * 8192;
        #pragma unroll
        for (int i = 0; i < 2; ++i) {
            int b = w * 2 + i;                     // W block 0..7
            gload_lds16(Ws + b * 1024 + l * 16, &ldsW[buf][b * 1024]);
        }
    };

    auto domfma = [&](int buf) {
        bf16x8 bh[4];
        #pragma unroll
        for (int nt = 0; nt < 4; ++nt)
            bh[nt] = *(const bf16x8*)(&ldsW[buf][wrbyte[nt]]);
        #pragma unroll
        for (int mt = 0; mt < 4; ++mt) {
            bf16x8 a = *(const bf16x8*)(&ldsA[buf][abyte[mt]]);
            #pragma unroll
            for (int nt = 0; nt < 4; ++nt)
                acc[mt][nt] = __builtin_amdgcn_mfma_f32_16x16x32_bf16(a, bh[nt], acc[mt][nt], 0, 0, 0);
        }
    };

    stage(0, 0);
    __syncthreads();
    #pragma unroll 1
    for (int s = 0; s < NT; ++s) {
        int buf = s & 1;
        if (s + 1 < NT) stage(s + 1, buf ^ 1);   // in flight over MFMAs
        domfma(buf);
        __syncthreads();
    }

    #pragma unroll
    for (int nt = 0; nt < 4; ++nt) {
        int col = cb * 128 + cw * 64 + nt * 16 + lr;
        float bv = bias[col];
        #pragma unroll
        for (int mt = 0; mt < 4; ++mt) {
            #pragma unroll
            for (int rr = 0; rr < 4; ++rr) {
                int grow = row0 + wr * 64 + mt * 16 + lg * 4 + rr;
                if (grow < n) {
                    float v = fmaxf(acc[mt][nt][rr] + bv, 0.f);
                    if (out)  out[(size_t)grow * 256 + col] = v;
                    if (outb) outb[(size_t)grow * 256 + col] = f2bf(v);
                }
            }
        }
    }
}

extern "C" void kernel_launch(void* const* d_in, const int* in_sizes, int n_in,
                              void* d_out, int out_size, void* d_ws, size_t ws_size,
                              hipStream_t stream) {
    const float* x   = (const float*)d_in[0];
    const int* edge  = (const int*)d_in[1];
    const float* Wl0 = (const float*)d_in[2];
    const float* bl0 = (const float*)d_in[3];
    const float* Wr0 = (const float*)d_in[4];
    const float* Wl1 = (const float*)d_in[5];
    const float* bl1 = (const float*)d_in[6];
    const float* Wr1 = (const float*)d_in[7];
    const float* Wl2 = (const float*)d_in[8];
    const float* bl2 = (const float*)d_in[9];
    const float* Wr2 = (const float*)d_in[10];

    int n = in_sizes[0] / 128;   // 50000
    int E = in_sizes[1] / 2;     // 800000
    int npad = n + 128;
    const int* src = edge;
    const int* dst = edge + E;

    char* wptr = (char*)d_ws;
    auto alloc = [&](size_t bytes) { char* p = wptr; wptr += align_up(bytes, 256); return p; };
    int*      deg    = (int*)alloc((size_t)n * 4);
    int*      rowptr = (int*)alloc(((size_t)n + 1) * 4);
    int*      rank   = (int*)alloc((size_t)E * 4);
    int*      csr    = (int*)alloc((size_t)E * 4);
    float*    invd   = (float*)alloc((size_t)n * 4);
    int*      bsums  = (int*)alloc(256 * 4);
    int*      boff   = (int*)alloc(256 * 4);
    uint8_t*  Wp0    = (uint8_t*)alloc(8 * 16384);
    uint8_t*  Wp1    = (uint8_t*)alloc(16 * 16384);
    uint8_t*  Wp2    = (uint8_t*)alloc(16 * 16384);
    uint16_t* xb     = (uint16_t*)alloc((size_t)npad * 128 * 2);
    uint16_t* aggb   = (uint16_t*)alloc((size_t)npad * 256 * 2);
    uint16_t* h0b    = (uint16_t*)alloc((size_t)npad * 256 * 2);
    uint16_t* h1b    = (uint16_t*)alloc((size_t)npad * 256 * 2);

    int NB = (n + 1023) / 1024;
    int cx = n * 128;
    int nb1 = (E + 255) / 256;
    int nb2 = (cx / 8 + 255) / 256;

    hipMemsetAsync(deg, 0, (size_t)n * 4, stream);
    prep_all<<<nb1 + nb2 + 320, 256, 0, stream>>>(dst, deg, rank, E, nb1,
                                                  x, xb, cx, nb2,
                                                  Wl0, Wr0, Wp0, Wl1, Wr1, Wp1,
                                                  Wl2, Wr2, Wp2);
    scan_a<<<NB, 256, 0, stream>>>(deg, bsums, n);
    scan_b<<<1, 256, 0, stream>>>(bsums, boff, NB, rowptr + n);
    scan_c<<<NB, 256, 0, stream>>>(deg, boff, rowptr, invd, n);
    fill_kernel<<<(E + 255) / 256, 256, 0, stream>>>(src, dst, rowptr, rank, csr, E);

    int gemm_grid = ((n + 127) / 128) * 2;   // 782
    // layer 0: C=128 -> 256
    agg_bf16<128><<<(n + 15) / 16, 256, 0, stream>>>(xb, rowptr, csr, invd, aggb, n);
    gemm_mfma<128><<<gemm_grid, 256, 0, stream>>>(aggb, xb, Wp0, bl0, (float*)nullptr, h0b, n, gemm_grid);
    // layer 1: 256 -> 256
    agg_bf16<256><<<(n + 7) / 8, 256, 0, stream>>>(h0b, rowptr, csr, invd, aggb, n);
    gemm_mfma<256><<<gemm_grid, 256, 0, stream>>>(aggb, h0b, Wp1, bl1, (float*)nullptr, h1b, n, gemm_grid);
    // layer 2: 256 -> 256 (fp32 output to d_out)
    agg_bf16<256><<<(n + 7) / 8, 256, 0, stream>>>(h1b, rowptr, csr, invd, aggb, n);
    gemm_mfma<256><<<gemm_grid, 256, 0, stream>>>(aggb, h1b, Wp2, bl2, (float*)d_out, (uint16_t*)nullptr, n, gemm_grid);
}